// Round 1
// baseline (125.690 us; speedup 1.0000x reference)
//
#include <hip/hip_runtime.h>
#include <hip/hip_bf16.h>

// GNNLayer: per-edge MLP score -> sampled segment-sum -> fc2 + BatchNorm.
// Key algebra: sum(h@w2.T+b2, axis=1) == h . colsum(w2) + sum(b2), and only
// the first min(64, group_len) edges per (sorted) head contribute.

#define D 128

typedef __attribute__((ext_vector_type(8))) short bf16x8;
typedef __attribute__((ext_vector_type(4))) float f32x4;

__device__ __forceinline__ unsigned short f2bf(float f) {
  union { float f; unsigned int u; } v; v.f = f;
  unsigned int r = v.u + 0x7FFFu + ((v.u >> 16) & 1u);
  return (unsigned short)(r >> 16);
}

// ---- prep: w1 -> bf16, starts[] via binary search, w2 colsum, b2 sum ----
__global__ void prep_kernel(const float* __restrict__ w1,
                            const float* __restrict__ w2,
                            const float* __restrict__ b2,
                            const int* __restrict__ head,
                            unsigned short* __restrict__ w1b,
                            int* __restrict__ starts,
                            float* __restrict__ w2s,
                            float* __restrict__ b2sum,
                            int E_total, int n_drug) {
  int g = blockIdx.x * 256 + threadIdx.x;
  if (g < D * D) w1b[g] = f2bf(w1[g]);
  if (g <= n_drug) {
    int lo = 0, hi = E_total;
    while (lo < hi) { int mid = (lo + hi) >> 1; if (head[mid] < g) lo = mid + 1; else hi = mid; }
    starts[g] = lo;
  }
  if (g < D) {
    float s = 0.f;
    for (int j = 0; j < D; ++j) s += w2[j * D + g];
    w2s[g] = s;
  }
  if (g == 0) {
    float s = 0.f;
    for (int j = 0; j < D; ++j) s += b2[j];
    b2sum[0] = s;
  }
}

// ---- per-drug: had = drug*rel -> z = had@w1^T + b1 (bf16 MFMA) -> sigmoid
// ---- -> score = h.w2s + b2sum -> neigh = sum score*tail ----
__global__ __launch_bounds__(256, 2) void edge_kernel(
    const float* __restrict__ drug_emb, const float* __restrict__ rel_emb,
    const float* __restrict__ tail_emb, const float* __restrict__ b1,
    const int* __restrict__ dkg_rel, const int* __restrict__ dkg_tail,
    const int* __restrict__ starts, const unsigned short* __restrict__ w1b,
    const float* __restrict__ w2s, const float* __restrict__ b2sum,
    const int* __restrict__ samp, float* __restrict__ neigh) {
  const int n = blockIdx.x;
  const int tid = threadIdx.x;
  const int w = tid >> 6, lane = tid & 63;
  const int fl = lane & 15, kh = lane >> 4;

  __shared__ __align__(16) unsigned short hadb[64][136];  // pad: +8 bf16 keeps 16B align, breaks bank stride
  __shared__ float scorePart[4][64];
  __shared__ float scoreL[64];
  __shared__ int   tails[64];

  const int base = starts[n];
  const int end  = starts[n + 1];
  int ss = samp[0]; if (ss > 64) ss = 64;
  int cnt = end - base; if (cnt > ss) cnt = ss; if (cnt < 0) cnt = 0;

  const int kk = tid & 127;
  const float drugk = drug_emb[n * D + kk];

  // stage had (bf16) for up to 64 kept edges
  for (int it = 0; it < 32; ++it) {
    int e = it * 2 + (tid >> 7);
    int r = 0;
    if (e < cnt) r = dkg_rel[base + e];
    float v = drugk * rel_emb[r * D + kk];
    hadb[e][kk] = f2bf(v);
  }
  if (tid < 64) tails[tid] = (tid < cnt) ? dkg_tail[base + tid] : 0;

  // B fragments: wave w covers feature tiles {2w, 2w+1}; frag = 8 consecutive k of w1 row f
  bf16x8 bfr[2][4];
  float w2sr[2], b1r[2];
  #pragma unroll
  for (int jq = 0; jq < 2; ++jq) {
    int f = (w * 2 + jq) * 16 + fl;
    w2sr[jq] = w2s[f];
    b1r[jq]  = b1[f];
    #pragma unroll
    for (int kt = 0; kt < 4; ++kt)
      bfr[jq][kt] = *(const bf16x8*)(w1b + f * D + kt * 32 + kh * 8);
  }
  const float b2s = b2sum[0];

  __syncthreads();

  f32x4 acc[4][2];
  #pragma unroll
  for (int mt = 0; mt < 4; ++mt)
    #pragma unroll
    for (int jq = 0; jq < 2; ++jq)
      acc[mt][jq] = (f32x4){0.f, 0.f, 0.f, 0.f};

  #pragma unroll
  for (int kt = 0; kt < 4; ++kt) {
    bf16x8 af[4];
    #pragma unroll
    for (int mt = 0; mt < 4; ++mt)
      af[mt] = *(const bf16x8*)&hadb[mt * 16 + fl][kt * 32 + kh * 8];
    #pragma unroll
    for (int mt = 0; mt < 4; ++mt)
      #pragma unroll
      for (int jq = 0; jq < 2; ++jq)
        acc[mt][jq] = __builtin_amdgcn_mfma_f32_16x16x32_bf16(af[mt], bfr[jq][kt], acc[mt][jq], 0, 0, 0);
  }

  // epilogue: sigmoid, partial score over this wave's 32 features, 16-lane reduce
  #pragma unroll
  for (int mt = 0; mt < 4; ++mt) {
    #pragma unroll
    for (int r = 0; r < 4; ++r) {
      float p = 0.f;
      #pragma unroll
      for (int jq = 0; jq < 2; ++jq) {
        float z = acc[mt][jq][r] + b1r[jq];
        float h = 1.f / (1.f + __expf(-z));
        p += h * w2sr[jq];
      }
      p += __shfl_xor(p, 1);
      p += __shfl_xor(p, 2);
      p += __shfl_xor(p, 4);
      p += __shfl_xor(p, 8);
      if (fl == 0) scorePart[w][mt * 16 + kh * 4 + r] = p;
    }
  }
  __syncthreads();

  if (tid < 64) {
    float sc = scorePart[0][tid] + scorePart[1][tid] + scorePart[2][tid] + scorePart[3][tid] + b2s;
    scoreL[tid] = (tid < cnt) ? sc : 0.f;
  }
  __syncthreads();

  if (tid < D) {
    float a = 0.f;
    for (int e = 0; e < cnt; ++e)
      a += scoreL[e] * tail_emb[(long)tails[e] * D + tid];
    neigh[n * D + tid] = a;
  }
}

// ---- fc2: out_pre[n][j] = [drug|neigh] . fc2_w[j][:] + fc2_b[j] ----
__global__ void fc2_kernel(const float* __restrict__ drug_emb,
                           const float* __restrict__ neigh,
                           const float* __restrict__ fc2_w,
                           const float* __restrict__ fc2_b,
                           float* __restrict__ out_pre) {
  __shared__ float cbuf[2][256];
  int tid = threadIdx.x;
  int s = tid >> 7, j = tid & 127;
  int n = blockIdx.x * 2 + s;
  cbuf[s][j]       = drug_emb[n * D + j];
  cbuf[s][D + j]   = neigh[n * D + j];
  __syncthreads();
  float a = fc2_b[j];
  const float4* wr = (const float4*)(fc2_w + j * 256);
  #pragma unroll 8
  for (int k4 = 0; k4 < 64; ++k4) {
    float4 wv = wr[k4];
    a += cbuf[s][k4 * 4 + 0] * wv.x + cbuf[s][k4 * 4 + 1] * wv.y +
         cbuf[s][k4 * 4 + 2] * wv.z + cbuf[s][k4 * 4 + 3] * wv.w;
  }
  out_pre[n * D + j] = a;
}

// ---- BN stats: partial sums (16 rows/block), then final reduce ----
__global__ void bnstat1_kernel(const float* __restrict__ out_pre, float* __restrict__ partial) {
  int tid = threadIdx.x;
  int j = tid & 127, h = tid >> 7;
  int n0 = blockIdx.x * 16 + h * 8;
  float s = 0.f, s2 = 0.f;
  #pragma unroll
  for (int r = 0; r < 8; ++r) {
    float v = out_pre[(n0 + r) * D + j];
    s += v; s2 += v * v;
  }
  __shared__ float sh[128][2];
  if (h == 1) { sh[j][0] = s; sh[j][1] = s2; }
  __syncthreads();
  if (h == 0) {
    s += sh[j][0]; s2 += sh[j][1];
    partial[(blockIdx.x * D + j) * 2 + 0] = s;
    partial[(blockIdx.x * D + j) * 2 + 1] = s2;
  }
}

__global__ void bnstat2_kernel(const float* __restrict__ partial,
                               const float* __restrict__ gamma,
                               const float* __restrict__ beta,
                               float* __restrict__ scaleshift,
                               int nblocks, int nrows) {
  int j = threadIdx.x;  // 128
  float s = 0.f, s2 = 0.f;
  for (int b = 0; b < nblocks; ++b) {
    s  += partial[(b * D + j) * 2 + 0];
    s2 += partial[(b * D + j) * 2 + 1];
  }
  float mean = s / (float)nrows;
  float var  = s2 / (float)nrows - mean * mean;
  float inv  = rsqrtf(var + 1e-5f);
  float sc   = inv * gamma[j];
  scaleshift[j]       = sc;
  scaleshift[D + j]   = beta[j] - mean * sc;
}

__global__ void finalize_kernel(const float* __restrict__ out_pre,
                                const float* __restrict__ scaleshift,
                                const float* __restrict__ x,
                                float* __restrict__ out, int total) {
  int i = blockIdx.x * blockDim.x + threadIdx.x;
  if (i < total) {
    int j = i & 127;
    out[i] = out_pre[i] * scaleshift[j] + scaleshift[D + j];
    out[total + i] = x[i];
  }
}

extern "C" void kernel_launch(void* const* d_in, const int* in_sizes, int n_in,
                              void* d_out, int out_size, void* d_ws, size_t ws_size,
                              hipStream_t stream) {
  const float* drug_emb = (const float*)d_in[0];
  const float* rel_emb  = (const float*)d_in[1];
  const float* tail_emb = (const float*)d_in[2];
  const float* w1       = (const float*)d_in[3];
  const float* b1       = (const float*)d_in[4];
  const float* w2       = (const float*)d_in[5];
  const float* b2       = (const float*)d_in[6];
  const float* fc2_w    = (const float*)d_in[7];
  const float* fc2_b    = (const float*)d_in[8];
  const float* gamma    = (const float*)d_in[9];
  const float* beta     = (const float*)d_in[10];
  const float* x        = (const float*)d_in[11];
  const int*   dkg_head = (const int*)d_in[12];
  const int*   dkg_rel  = (const int*)d_in[13];
  const int*   dkg_tail = (const int*)d_in[14];
  const int*   samp     = (const int*)d_in[15];

  const int n_drug = in_sizes[0] / D;   // 2000
  const int E      = in_sizes[12];      // 500000
  float* out = (float*)d_out;
  const int total = out_size / 2;       // 256000

  // workspace layout
  char* ws = (char*)d_ws;
  int*            starts  = (int*)(ws + 0);            // (n_drug+1) ints -> 8192 B
  unsigned short* w1b     = (unsigned short*)(ws + 8192);       // 32768 B
  float*          w2s     = (float*)(ws + 8192 + 32768);        // 512 B
  float*          b2sum   = (float*)(ws + 8192 + 32768 + 512);  // 4 B -> pad
  float*          neigh   = (float*)(ws + 65536);               // 1,024,000 B
  float*          out_pre = (float*)(ws + 65536 + 1024000);     // 1,024,000 B
  float*          partial = (float*)(ws + 65536 + 2048000);     // 128,000 B
  float*          scsh    = (float*)(ws + 65536 + 2048000 + 131072);  // 1 KB

  const int nb1 = n_drug / 16;  // 125

  hipLaunchKernelGGL(prep_kernel, dim3(64), dim3(256), 0, stream,
                     w1, w2, b2, dkg_head, w1b, starts, w2s, b2sum, E, n_drug);
  hipLaunchKernelGGL(edge_kernel, dim3(n_drug), dim3(256), 0, stream,
                     drug_emb, rel_emb, tail_emb, b1, dkg_rel, dkg_tail,
                     starts, w1b, w2s, b2sum, samp, neigh);
  hipLaunchKernelGGL(fc2_kernel, dim3(n_drug / 2), dim3(256), 0, stream,
                     drug_emb, neigh, fc2_w, fc2_b, out_pre);
  hipLaunchKernelGGL(bnstat1_kernel, dim3(nb1), dim3(256), 0, stream, out_pre, partial);
  hipLaunchKernelGGL(bnstat2_kernel, dim3(1), dim3(128), 0, stream,
                     partial, gamma, beta, scsh, nb1, n_drug);
  hipLaunchKernelGGL(finalize_kernel, dim3((total + 255) / 256), dim3(256), 0, stream,
                     out_pre, scsh, x, out, total);
}

// Round 2
// 81.785 us; speedup vs baseline: 1.5368x; 1.5368x over previous
//
#include <hip/hip_runtime.h>
#include <hip/hip_bf16.h>

// GNNLayer: per-edge MLP score -> sampled segment-sum -> fc2 + BatchNorm.
// Algebra: sum(h@w2.T+b2, axis=1) == h . colsum(w2) + sum(b2); only the first
// min(64, group_len) edges per (sorted) head contribute.

#define D 128

typedef __attribute__((ext_vector_type(8))) short bf16x8;
typedef __attribute__((ext_vector_type(4))) float f32x4;
typedef __attribute__((ext_vector_type(4))) unsigned short u16x4;

__device__ __forceinline__ unsigned short f2bf(float f) {
  union { float f; unsigned int u; } v; v.f = f;
  unsigned int r = v.u + 0x7FFFu + ((v.u >> 16) & 1u);
  return (unsigned short)(r >> 16);
}

// ---- prep: edge-parallel starts[] scatter, w1->bf16, w2 colsum, b2 sum ----
__global__ void prep_kernel(const float* __restrict__ w1,
                            const float* __restrict__ w2,
                            const float* __restrict__ b2,
                            const int* __restrict__ head,
                            unsigned short* __restrict__ w1b,
                            int* __restrict__ starts,
                            float* __restrict__ w2s,
                            float* __restrict__ b2sum,
                            int E_total, int n_drug) {
  int g = blockIdx.x * 256 + threadIdx.x;
  if (g < E_total) {
    int h1 = head[g];
    int h0 = (g == 0) ? -1 : head[g - 1];
    for (int d = h0 + 1; d <= h1; ++d) starts[d] = g;   // usually 0 iters
    if (g == E_total - 1) {
      for (int d = h1 + 1; d <= n_drug; ++d) starts[d] = E_total;
    }
  }
  if (g < D * D) w1b[g] = f2bf(w1[g]);
  if (g < D) {
    float s = 0.f;
    for (int j = 0; j < D; ++j) s += w2[j * D + g];
    w2s[g] = s;
  }
  if (g == 0) {
    float s = 0.f;
    for (int j = 0; j < D; ++j) s += b2[j];
    b2sum[0] = s;
  }
}

// ---- per-drug: had = drug*rel -> z = had@w1^T + b1 (bf16 MFMA) -> sigmoid
// ---- -> score = h.w2s + b2sum -> neigh = sum score*tail ----
__global__ __launch_bounds__(256, 2) void edge_kernel(
    const float* __restrict__ drug_emb, const float* __restrict__ rel_emb,
    const float* __restrict__ tail_emb, const float* __restrict__ b1,
    const int* __restrict__ dkg_rel, const int* __restrict__ dkg_tail,
    const int* __restrict__ starts, const unsigned short* __restrict__ w1b,
    const float* __restrict__ w2s, const float* __restrict__ b2sum,
    const int* __restrict__ samp, float* __restrict__ neigh) {
  const int n = blockIdx.x;
  const int tid = threadIdx.x;
  const int w = tid >> 6, lane = tid & 63;
  const int fl = lane & 15, kh = lane >> 4;
  const int g = tid >> 5, l5 = tid & 31;   // 8 groups x 32 lanes

  __shared__ __align__(16) unsigned short hadb[64][136];  // 17408 B (272B row = 16B-aligned)
  __shared__ float scorePart[4][64];
  __shared__ float scoreL[64];
  __shared__ int   tails[64];
  float* gpart = (float*)&hadb[0][0];  // alias: gather partials (4KB), used after MFMA phase

  const int base = starts[n];
  const int end  = starts[n + 1];
  int ss = samp[0]; if (ss > 64) ss = 64;
  int cnt = end - base; if (cnt > ss) cnt = ss; if (cnt < 0) cnt = 0;

  if (tid < 64) tails[tid] = (tid < cnt) ? dkg_tail[base + tid] : 0;

  // stage had (bf16): group g handles edges it*8+g; 32 lanes cover 128 feats via float4
  const f32x4 dr = *(const f32x4*)(drug_emb + (long)n * D + l5 * 4);
  #pragma unroll
  for (int it = 0; it < 8; ++it) {
    int e = it * 8 + g;
    int r = (e < cnt) ? dkg_rel[base + e] : 0;
    f32x4 rl = *(const f32x4*)(rel_emb + (long)r * D + l5 * 4);
    f32x4 v = dr * rl;
    u16x4 pk = { f2bf(v.x), f2bf(v.y), f2bf(v.z), f2bf(v.w) };
    *(u16x4*)&hadb[e][l5 * 4] = pk;
  }

  // B fragments: wave w covers feature tiles {2w, 2w+1}
  bf16x8 bfr[2][4];
  float w2sr[2], b1r[2];
  #pragma unroll
  for (int jq = 0; jq < 2; ++jq) {
    int f = (w * 2 + jq) * 16 + fl;
    w2sr[jq] = w2s[f];
    b1r[jq]  = b1[f];
    #pragma unroll
    for (int kt = 0; kt < 4; ++kt)
      bfr[jq][kt] = *(const bf16x8*)(w1b + f * D + kt * 32 + kh * 8);
  }
  const float b2s = b2sum[0];

  __syncthreads();

  // acc init = b1 (C/D col is lane-constant -> b1 same across the 4 regs)
  f32x4 acc[4][2];
  #pragma unroll
  for (int mt = 0; mt < 4; ++mt)
    #pragma unroll
    for (int jq = 0; jq < 2; ++jq)
      acc[mt][jq] = (f32x4){b1r[jq], b1r[jq], b1r[jq], b1r[jq]};

  #pragma unroll
  for (int kt = 0; kt < 4; ++kt) {
    bf16x8 af[4];
    #pragma unroll
    for (int mt = 0; mt < 4; ++mt)
      af[mt] = *(const bf16x8*)&hadb[mt * 16 + fl][kt * 32 + kh * 8];
    #pragma unroll
    for (int mt = 0; mt < 4; ++mt)
      #pragma unroll
      for (int jq = 0; jq < 2; ++jq)
        acc[mt][jq] = __builtin_amdgcn_mfma_f32_16x16x32_bf16(af[mt], bfr[jq][kt], acc[mt][jq], 0, 0, 0);
  }

  // epilogue: sigmoid, partial score over this wave's 32 features, 16-lane reduce
  #pragma unroll
  for (int mt = 0; mt < 4; ++mt) {
    #pragma unroll
    for (int r = 0; r < 4; ++r) {
      float p = 0.f;
      #pragma unroll
      for (int jq = 0; jq < 2; ++jq) {
        float hh = 1.f / (1.f + __expf(-acc[mt][jq][r]));
        p += hh * w2sr[jq];
      }
      p += __shfl_xor(p, 1);
      p += __shfl_xor(p, 2);
      p += __shfl_xor(p, 4);
      p += __shfl_xor(p, 8);
      if (fl == 0) scorePart[w][mt * 16 + kh * 4 + r] = p;
    }
  }
  __syncthreads();

  if (tid < 64) {
    float sc = scorePart[0][tid] + scorePart[1][tid] + scorePart[2][tid] + scorePart[3][tid] + b2s;
    scoreL[tid] = (tid < cnt) ? sc : 0.f;
  }
  __syncthreads();

  // gather: group g owns edges it*8+g, float4 rows -> 8x more loads in flight
  f32x4 a = (f32x4){0.f, 0.f, 0.f, 0.f};
  #pragma unroll
  for (int it = 0; it < 8; ++it) {
    int e = it * 8 + g;
    if (e < cnt) {
      float s = scoreL[e];
      f32x4 row = *(const f32x4*)(tail_emb + (long)tails[e] * D + l5 * 4);
      a += row * s;
    }
  }
  ((f32x4*)gpart)[g * 32 + l5] = a;  // safe: hadb reads all done before prior barrier
  __syncthreads();

  if (tid < D) {
    float s = 0.f;
    #pragma unroll
    for (int q = 0; q < 8; ++q) s += gpart[q * 128 + tid];
    neigh[(long)n * D + tid] = s;
  }
}

// ---- fc2 + BN partial stats fused ----
__global__ __launch_bounds__(256, 2) void fc2s_kernel(
    const float* __restrict__ drug_emb, const float* __restrict__ neigh,
    const float* __restrict__ fc2_w, const float* __restrict__ fc2_b,
    float* __restrict__ out_pre, float* __restrict__ partial) {
  __shared__ float cbuf[16][256];
  __shared__ float sst[2][128][2];
  const int tid = threadIdx.x;
  const int n0 = blockIdx.x * 16;
  #pragma unroll
  for (int it = 0; it < 16; ++it) {
    int idx = it * 256 + tid;
    int r = idx >> 8, c = idx & 255;
    cbuf[r][c] = (c < 128) ? drug_emb[(long)(n0 + r) * D + c]
                           : neigh[(long)(n0 + r) * D + (c - 128)];
  }
  __syncthreads();
  const int j = tid & 127, h = tid >> 7;
  float acc[8];
  float bj = fc2_b[j];
  #pragma unroll
  for (int r = 0; r < 8; ++r) acc[r] = bj;
  const f32x4* wr = (const f32x4*)(fc2_w + (long)j * 256);
  #pragma unroll 4
  for (int k4 = 0; k4 < 64; ++k4) {
    f32x4 wv = wr[k4];
    #pragma unroll
    for (int r = 0; r < 8; ++r) {
      f32x4 cv = *(const f32x4*)&cbuf[h * 8 + r][k4 * 4];
      acc[r] += cv.x * wv.x + cv.y * wv.y + cv.z * wv.z + cv.w * wv.w;
    }
  }
  float s = 0.f, s2 = 0.f;
  #pragma unroll
  for (int r = 0; r < 8; ++r) {
    out_pre[(long)(n0 + h * 8 + r) * D + j] = acc[r];
    s += acc[r]; s2 += acc[r] * acc[r];
  }
  sst[h][j][0] = s; sst[h][j][1] = s2;
  __syncthreads();
  if (h == 0) {
    partial[((long)blockIdx.x * D + j) * 2 + 0] = s + sst[1][j][0];
    partial[((long)blockIdx.x * D + j) * 2 + 1] = s2 + sst[1][j][1];
  }
}

__global__ void bnstat2_kernel(const float* __restrict__ partial,
                               const float* __restrict__ gamma,
                               const float* __restrict__ beta,
                               float* __restrict__ scaleshift,
                               int nblocks, int nrows) {
  const int tid = threadIdx.x;           // 256
  const int j = tid & 127, h = tid >> 7;
  float s = 0.f, s2 = 0.f;
  for (int b = h; b < nblocks; b += 2) {
    s  += partial[(b * D + j) * 2 + 0];
    s2 += partial[(b * D + j) * 2 + 1];
  }
  __shared__ float sh[128][2];
  if (h == 1) { sh[j][0] = s; sh[j][1] = s2; }
  __syncthreads();
  if (h == 0) {
    s += sh[j][0]; s2 += sh[j][1];
    float mean = s / (float)nrows;
    float var  = s2 / (float)nrows - mean * mean;
    float inv  = rsqrtf(var + 1e-5f);
    float sc   = inv * gamma[j];
    scaleshift[j]     = sc;
    scaleshift[D + j] = beta[j] - mean * sc;
  }
}

__global__ void finalize_kernel(const float* __restrict__ out_pre,
                                const float* __restrict__ scaleshift,
                                const float* __restrict__ x,
                                float* __restrict__ out, int total) {
  int i = blockIdx.x * blockDim.x + threadIdx.x;
  if (i < total) {
    int j = i & 127;
    out[i] = out_pre[i] * scaleshift[j] + scaleshift[D + j];
    out[total + i] = x[i];
  }
}

extern "C" void kernel_launch(void* const* d_in, const int* in_sizes, int n_in,
                              void* d_out, int out_size, void* d_ws, size_t ws_size,
                              hipStream_t stream) {
  const float* drug_emb = (const float*)d_in[0];
  const float* rel_emb  = (const float*)d_in[1];
  const float* tail_emb = (const float*)d_in[2];
  const float* w1       = (const float*)d_in[3];
  const float* b1       = (const float*)d_in[4];
  const float* w2       = (const float*)d_in[5];
  const float* b2       = (const float*)d_in[6];
  const float* fc2_w    = (const float*)d_in[7];
  const float* fc2_b    = (const float*)d_in[8];
  const float* gamma    = (const float*)d_in[9];
  const float* beta     = (const float*)d_in[10];
  const float* x        = (const float*)d_in[11];
  const int*   dkg_rel  = (const int*)d_in[13];
  const int*   dkg_tail = (const int*)d_in[14];
  const int*   samp     = (const int*)d_in[15];
  const int*   dkg_head = (const int*)d_in[12];

  const int n_drug = in_sizes[0] / D;   // 2000
  const int E      = in_sizes[12];      // 500000
  float* out = (float*)d_out;
  const int total = out_size / 2;       // 256000

  // workspace layout
  char* ws = (char*)d_ws;
  int*            starts  = (int*)(ws + 0);                     // 8192 B
  unsigned short* w1b     = (unsigned short*)(ws + 8192);       // 32768 B
  float*          w2s     = (float*)(ws + 8192 + 32768);        // 512 B
  float*          b2sum   = (float*)(ws + 8192 + 32768 + 512);  // 4 B
  float*          neigh   = (float*)(ws + 65536);               // 1,024,000 B
  float*          out_pre = (float*)(ws + 65536 + 1024000);     // 1,024,000 B
  float*          partial = (float*)(ws + 65536 + 2048000);     // 128,000 B
  float*          scsh    = (float*)(ws + 65536 + 2048000 + 131072);  // 1 KB

  const int nb2 = n_drug / 16;  // 125 fc2s blocks

  hipLaunchKernelGGL(prep_kernel, dim3((E + 256) / 256), dim3(256), 0, stream,
                     w1, w2, b2, dkg_head, w1b, starts, w2s, b2sum, E, n_drug);
  hipLaunchKernelGGL(edge_kernel, dim3(n_drug), dim3(256), 0, stream,
                     drug_emb, rel_emb, tail_emb, b1, dkg_rel, dkg_tail,
                     starts, w1b, w2s, b2sum, samp, neigh);
  hipLaunchKernelGGL(fc2s_kernel, dim3(nb2), dim3(256), 0, stream,
                     drug_emb, neigh, fc2_w, fc2_b, out_pre, partial);
  hipLaunchKernelGGL(bnstat2_kernel, dim3(1), dim3(256), 0, stream,
                     partial, gamma, beta, scsh, nb2, n_drug);
  hipLaunchKernelGGL(finalize_kernel, dim3((total + 255) / 256), dim3(256), 0, stream,
                     out_pre, scsh, x, out, total);
}

// Round 3
// 53.020 us; speedup vs baseline: 2.3706x; 1.5425x over previous
//
#include <hip/hip_runtime.h>
#include <hip/hip_bf16.h>

// GNNLayer: per-edge MLP score -> sampled segment-sum -> fc2 + BatchNorm.
// Algebra: sum(h@w2.T+b2, axis=1) == h . colsum(w2) + sum(b2); only the first
// min(64, group_len) edges per (sorted) head contribute. fc2 runs as bf16 MFMA
// over [drug|neigh] rows staged in LDS.

#define D 128

typedef __attribute__((ext_vector_type(8))) short bf16x8;
typedef __attribute__((ext_vector_type(8))) unsigned short u16x8;
typedef __attribute__((ext_vector_type(4))) float f32x4;
typedef __attribute__((ext_vector_type(4))) unsigned short u16x4;

__device__ __forceinline__ unsigned short f2bf(float f) {
  union { float f; unsigned int u; } v; v.f = f;
  unsigned int r = v.u + 0x7FFFu + ((v.u >> 16) & 1u);
  return (unsigned short)(r >> 16);
}

// ---- prep: starts[] scatter, bf16 conversions, w2 colsum, b2 sum, x-copy ----
__global__ void prep_kernel(const float* __restrict__ w1,
                            const float* __restrict__ w2,
                            const float* __restrict__ b2,
                            const float* __restrict__ drug_emb,
                            const float* __restrict__ fc2_w,
                            const float* __restrict__ x,
                            const int* __restrict__ head,
                            unsigned short* __restrict__ w1b,
                            unsigned short* __restrict__ drugb,
                            unsigned short* __restrict__ fc2wb,
                            int* __restrict__ starts,
                            float* __restrict__ w2s,
                            float* __restrict__ b2sum,
                            float* __restrict__ out_hi,
                            int E_total, int n_drug, int total) {
  int g = blockIdx.x * 256 + threadIdx.x;
  if (g < E_total) {
    int h1 = head[g];
    int h0 = (g == 0) ? -1 : head[g - 1];
    for (int d = h0 + 1; d <= h1; ++d) starts[d] = g;   // usually 0 iters
    if (g == E_total - 1) {
      for (int d = h1 + 1; d <= n_drug; ++d) starts[d] = E_total;
    }
  }
  if (g < D * D) w1b[g] = f2bf(w1[g]);
  if (g < 2 * D * D) fc2wb[g] = f2bf(fc2_w[g]);
  if (g < n_drug * D) drugb[g] = f2bf(drug_emb[g]);
  if (g < total) out_hi[g] = x[g];
  if (g < D) {
    float s = 0.f;
    for (int j = 0; j < D; ++j) s += w2[j * D + g];
    w2s[g] = s;
  }
  if (g == 0) {
    float s = 0.f;
    for (int j = 0; j < D; ++j) s += b2[j];
    b2sum[0] = s;
  }
}

// ---- per-drug: had = drug*rel -> z = had@w1^T + b1 (bf16 MFMA) -> sigmoid
// ---- -> score = h.w2s + b2sum -> neigh = sum score*tail (bf16 out) ----
__global__ __launch_bounds__(256, 2) void edge_kernel(
    const float* __restrict__ drug_emb, const float* __restrict__ rel_emb,
    const float* __restrict__ tail_emb, const float* __restrict__ b1,
    const int* __restrict__ dkg_rel, const int* __restrict__ dkg_tail,
    const int* __restrict__ starts, const unsigned short* __restrict__ w1b,
    const float* __restrict__ w2s, const float* __restrict__ b2sum,
    const int* __restrict__ samp, unsigned short* __restrict__ neighb) {
  const int n = blockIdx.x;
  const int tid = threadIdx.x;
  const int w = tid >> 6, lane = tid & 63;
  const int fl = lane & 15, kh = lane >> 4;
  const int g = tid >> 5, l5 = tid & 31;   // 8 groups x 32 lanes

  __shared__ __align__(16) unsigned short hadb[64][136];  // 272B row: 16B-aligned, 2-way bank alias only
  __shared__ float scorePart[4][64];
  __shared__ float scoreL[64];
  __shared__ int   tails[64];
  __shared__ int   relIdx[64];
  float* gpart = (float*)&hadb[0][0];  // alias: gather partials (4KB), used after MFMA phase

  const int base = starts[n];
  const int end  = starts[n + 1];
  int ss = samp[0]; if (ss > 64) ss = 64;
  int cnt = end - base; if (cnt > ss) cnt = ss; if (cnt < 0) cnt = 0;

  if (tid < 64) {
    tails[tid]  = (tid < cnt) ? dkg_tail[base + tid] : 0;
    relIdx[tid] = (tid < cnt) ? dkg_rel[base + tid] : 0;
  }

  const f32x4 dr = *(const f32x4*)(drug_emb + (long)n * D + l5 * 4);

  // B fragments: wave w covers feature tiles {2w, 2w+1} (global loads, pre-barrier)
  bf16x8 bfr[2][4];
  float w2sr[2], b1r[2];
  #pragma unroll
  for (int jq = 0; jq < 2; ++jq) {
    int f = (w * 2 + jq) * 16 + fl;
    w2sr[jq] = w2s[f];
    b1r[jq]  = b1[f];
    #pragma unroll
    for (int kt = 0; kt < 4; ++kt)
      bfr[jq][kt] = *(const bf16x8*)(w1b + f * D + kt * 32 + kh * 8);
  }
  const float b2s = b2sum[0];

  __syncthreads();  // relIdx/tails ready

  // stage had (bf16): group g handles edges it*8+g; 32 lanes cover 128 feats via float4
  #pragma unroll
  for (int it = 0; it < 8; ++it) {
    int e = it * 8 + g;
    int r = relIdx[e];                     // LDS broadcast, no dependent global load
    f32x4 rl = *(const f32x4*)(rel_emb + (long)r * D + l5 * 4);
    f32x4 v = dr * rl;
    u16x4 pk = { f2bf(v.x), f2bf(v.y), f2bf(v.z), f2bf(v.w) };
    *(u16x4*)&hadb[e][l5 * 4] = pk;
  }

  __syncthreads();

  // acc init = b1 (C/D col is lane-constant -> b1 same across the 4 regs)
  f32x4 acc[4][2];
  #pragma unroll
  for (int mt = 0; mt < 4; ++mt)
    #pragma unroll
    for (int jq = 0; jq < 2; ++jq)
      acc[mt][jq] = (f32x4){b1r[jq], b1r[jq], b1r[jq], b1r[jq]};

  #pragma unroll
  for (int kt = 0; kt < 4; ++kt) {
    bf16x8 af[4];
    #pragma unroll
    for (int mt = 0; mt < 4; ++mt)
      af[mt] = *(const bf16x8*)&hadb[mt * 16 + fl][kt * 32 + kh * 8];
    #pragma unroll
    for (int mt = 0; mt < 4; ++mt)
      #pragma unroll
      for (int jq = 0; jq < 2; ++jq)
        acc[mt][jq] = __builtin_amdgcn_mfma_f32_16x16x32_bf16(af[mt], bfr[jq][kt], acc[mt][jq], 0, 0, 0);
  }

  // epilogue: sigmoid, partial score over this wave's 32 features, 16-lane reduce
  #pragma unroll
  for (int mt = 0; mt < 4; ++mt) {
    #pragma unroll
    for (int r = 0; r < 4; ++r) {
      float p = 0.f;
      #pragma unroll
      for (int jq = 0; jq < 2; ++jq) {
        float hh = 1.f / (1.f + __expf(-acc[mt][jq][r]));
        p += hh * w2sr[jq];
      }
      p += __shfl_xor(p, 1);
      p += __shfl_xor(p, 2);
      p += __shfl_xor(p, 4);
      p += __shfl_xor(p, 8);
      if (fl == 0) scorePart[w][mt * 16 + kh * 4 + r] = p;
    }
  }
  __syncthreads();

  if (tid < 64) {
    float sc = scorePart[0][tid] + scorePart[1][tid] + scorePart[2][tid] + scorePart[3][tid] + b2s;
    scoreL[tid] = (tid < cnt) ? sc : 0.f;
  }
  __syncthreads();

  // gather: group g owns edges it*8+g, float4 rows
  f32x4 a = (f32x4){0.f, 0.f, 0.f, 0.f};
  #pragma unroll
  for (int it = 0; it < 8; ++it) {
    int e = it * 8 + g;
    if (e < cnt) {
      float s = scoreL[e];
      f32x4 row = *(const f32x4*)(tail_emb + (long)tails[e] * D + l5 * 4);
      a += row * s;
    }
  }
  ((f32x4*)gpart)[g * 32 + l5] = a;  // hadb fully consumed 2 barriers ago
  __syncthreads();

  if (tid < D) {
    float s = 0.f;
    #pragma unroll
    for (int q = 0; q < 8; ++q) s += gpart[q * 128 + tid];
    neighb[(long)n * D + tid] = f2bf(s);
  }
}

// ---- fc2 via bf16 MFMA + fused BN partial stats: 64 rows/block ----
__global__ __launch_bounds__(256, 1) void fc2s_kernel(
    const unsigned short* __restrict__ drugb, const unsigned short* __restrict__ neighb,
    const unsigned short* __restrict__ fc2wb, const float* __restrict__ fc2_b,
    float* __restrict__ out_pre, float* __restrict__ partial, int n_drug) {
  const int tid = threadIdx.x;
  const int w = tid >> 6, lane = tid & 63;
  const int fl = lane & 15, kh = lane >> 4;
  const int n0 = blockIdx.x * 64;

  __shared__ __align__(16) unsigned short asmem[64][264];  // 528B row stride: 2-way alias only

  // stage A: 64 rows x 512B ([drug|neigh] bf16); 2048 16B chunks over 8 iters
  #pragma unroll
  for (int it = 0; it < 8; ++it) {
    int c = it * 256 + tid;
    int row = c >> 5;
    int off = (c & 31) * 16;     // byte offset within 512B logical row
    int gr = n0 + row;
    u16x8 v = (u16x8){0,0,0,0,0,0,0,0};
    if (gr < n_drug) {
      const unsigned short* src = (off < 256) ? (drugb + (long)gr * D + (off >> 1))
                                              : (neighb + (long)gr * D + ((off - 256) >> 1));
      v = *(const u16x8*)src;
    }
    *(u16x8*)((char*)&asmem[0][0] + row * 528 + off) = v;
  }

  // B fragments: wave w covers output tiles {2w, 2w+1}; K=256 -> 8 kt
  bf16x8 bfr[2][8];
  float bjr[2];
  #pragma unroll
  for (int jq = 0; jq < 2; ++jq) {
    int f = (w * 2 + jq) * 16 + fl;
    bjr[jq] = fc2_b[f];
    #pragma unroll
    for (int kt = 0; kt < 8; ++kt)
      bfr[jq][kt] = *(const bf16x8*)(fc2wb + (long)f * 256 + kt * 32 + kh * 8);
  }
  __syncthreads();

  f32x4 acc[4][2];
  #pragma unroll
  for (int mt = 0; mt < 4; ++mt)
    #pragma unroll
    for (int jq = 0; jq < 2; ++jq)
      acc[mt][jq] = (f32x4){bjr[jq], bjr[jq], bjr[jq], bjr[jq]};

  #pragma unroll
  for (int kt = 0; kt < 8; ++kt) {
    bf16x8 af[4];
    #pragma unroll
    for (int mt = 0; mt < 4; ++mt)
      af[mt] = *(const bf16x8*)((char*)&asmem[0][0] + (mt * 16 + fl) * 528 + kt * 64 + kh * 16);
    #pragma unroll
    for (int mt = 0; mt < 4; ++mt)
      #pragma unroll
      for (int jq = 0; jq < 2; ++jq)
        acc[mt][jq] = __builtin_amdgcn_mfma_f32_16x16x32_bf16(af[mt], bfr[jq][kt], acc[mt][jq], 0, 0, 0);
  }

  // write out_pre + per-column BN partials (reduce across kh via shfl)
  #pragma unroll
  for (int jq = 0; jq < 2; ++jq) {
    int j = (w * 2 + jq) * 16 + fl;
    float s = 0.f, s2 = 0.f;
    #pragma unroll
    for (int mt = 0; mt < 4; ++mt) {
      #pragma unroll
      for (int r = 0; r < 4; ++r) {
        int grow = n0 + mt * 16 + kh * 4 + r;
        float v = acc[mt][jq][r];
        if (grow < n_drug) {
          out_pre[(long)grow * D + j] = v;
          s += v; s2 += v * v;
        }
      }
    }
    s  += __shfl_xor(s, 16);  s  += __shfl_xor(s, 32);
    s2 += __shfl_xor(s2, 16); s2 += __shfl_xor(s2, 32);
    if (kh == 0) {
      partial[((long)blockIdx.x * D + j) * 2 + 0] = s;
      partial[((long)blockIdx.x * D + j) * 2 + 1] = s2;
    }
  }
}

__global__ void bnstat2_kernel(const float* __restrict__ partial,
                               const float* __restrict__ gamma,
                               const float* __restrict__ beta,
                               float* __restrict__ scaleshift,
                               int nblocks, int nrows) {
  const int tid = threadIdx.x;           // 256
  const int j = tid & 127, h = tid >> 7;
  float s = 0.f, s2 = 0.f;
  for (int b = h; b < nblocks; b += 2) {
    s  += partial[(b * D + j) * 2 + 0];
    s2 += partial[(b * D + j) * 2 + 1];
  }
  __shared__ float sh[128][2];
  if (h == 1) { sh[j][0] = s; sh[j][1] = s2; }
  __syncthreads();
  if (h == 0) {
    s += sh[j][0]; s2 += sh[j][1];
    float mean = s / (float)nrows;
    float var  = s2 / (float)nrows - mean * mean;
    float inv  = rsqrtf(var + 1e-5f);
    float sc   = inv * gamma[j];
    scaleshift[j]     = sc;
    scaleshift[D + j] = beta[j] - mean * sc;
  }
}

__global__ void finalize_kernel(const float* __restrict__ out_pre,
                                const float* __restrict__ scaleshift,
                                float* __restrict__ out, int total4) {
  int i = blockIdx.x * blockDim.x + threadIdx.x;
  if (i < total4) {
    f32x4 v = ((const f32x4*)out_pre)[i];
    int j4 = (i & 31) * 4;
    f32x4 sc = *(const f32x4*)(scaleshift + j4);
    f32x4 sh = *(const f32x4*)(scaleshift + D + j4);
    v = v * sc + sh;
    ((f32x4*)out)[i] = v;
  }
}

extern "C" void kernel_launch(void* const* d_in, const int* in_sizes, int n_in,
                              void* d_out, int out_size, void* d_ws, size_t ws_size,
                              hipStream_t stream) {
  const float* drug_emb = (const float*)d_in[0];
  const float* rel_emb  = (const float*)d_in[1];
  const float* tail_emb = (const float*)d_in[2];
  const float* w1       = (const float*)d_in[3];
  const float* b1       = (const float*)d_in[4];
  const float* w2       = (const float*)d_in[5];
  const float* b2       = (const float*)d_in[6];
  const float* fc2_w    = (const float*)d_in[7];
  const float* fc2_b    = (const float*)d_in[8];
  const float* gamma    = (const float*)d_in[9];
  const float* beta     = (const float*)d_in[10];
  const float* x        = (const float*)d_in[11];
  const int*   dkg_head = (const int*)d_in[12];
  const int*   dkg_rel  = (const int*)d_in[13];
  const int*   dkg_tail = (const int*)d_in[14];
  const int*   samp     = (const int*)d_in[15];

  const int n_drug = in_sizes[0] / D;   // 2000
  const int E      = in_sizes[12];      // 500000
  float* out = (float*)d_out;
  const int total = out_size / 2;       // 256000

  // workspace layout
  char* ws = (char*)d_ws;
  int*            starts  = (int*)(ws + 0);                     // 8004 B
  unsigned short* w1b     = (unsigned short*)(ws + 8192);       // 32768 B
  float*          w2s     = (float*)(ws + 40960);               // 512 B
  float*          b2sum   = (float*)(ws + 41472);               // 4 B
  unsigned short* fc2wb   = (unsigned short*)(ws + 49152);      // 65536 B
  unsigned short* drugb   = (unsigned short*)(ws + 131072);     // 512000 B
  unsigned short* neighb  = (unsigned short*)(ws + 655360);     // 512000 B
  float*          out_pre = (float*)(ws + 1179648);             // 1024000 B
  float*          partial = (float*)(ws + 2228224);             // 32768 B
  float*          scsh    = (float*)(ws + 2269184);             // 1024 B

  const int nbf = (n_drug + 63) / 64;   // 32 fc2s blocks

  hipLaunchKernelGGL(prep_kernel, dim3((E + 256) / 256), dim3(256), 0, stream,
                     w1, w2, b2, drug_emb, fc2_w, x, dkg_head,
                     w1b, drugb, fc2wb, starts, w2s, b2sum, out + total,
                     E, n_drug, total);
  hipLaunchKernelGGL(edge_kernel, dim3(n_drug), dim3(256), 0, stream,
                     drug_emb, rel_emb, tail_emb, b1, dkg_rel, dkg_tail,
                     starts, w1b, w2s, b2sum, samp, neighb);
  hipLaunchKernelGGL(fc2s_kernel, dim3(nbf), dim3(256), 0, stream,
                     drugb, neighb, fc2wb, fc2_b, out_pre, partial, n_drug);
  hipLaunchKernelGGL(bnstat2_kernel, dim3(1), dim3(256), 0, stream,
                     partial, gamma, beta, scsh, nbf, n_drug);
  hipLaunchKernelGGL(finalize_kernel, dim3((total / 4 + 255) / 256), dim3(256), 0, stream,
                     out_pre, scsh, out, total / 4);
}